// Round 1
// baseline (1082.992 us; speedup 1.0000x reference)
//
#include <hip/hip_runtime.h>
#include <hip/hip_bf16.h>
#include <math.h>

// Problem constants
#define LAYERS 2
#define BSZ 4
#define PSZ 256
#define HDIM 768
#define NDIM 16
#define KDIM 4
#define DIN 1536
#define RDIM 49
#define TT 1024           // B*P
#define XDB_W 81          // R + 2*N
#define EPS 1e-5f

// ---------------- utility kernels ----------------

__global__ __launch_bounds__(256) void copy_kernel(const float* __restrict__ src,
                                                   float* __restrict__ dst, int n) {
    int i = blockIdx.x * 256 + threadIdx.x;
    for (; i < n; i += gridDim.x * 256) dst[i] = src[i];
}

// One block (256 threads) per row of length HDIM.
__global__ __launch_bounds__(256) void rmsnorm_kernel(const float* __restrict__ x,
                                                      const float* __restrict__ w,
                                                      float* __restrict__ out) {
    int t = blockIdx.x;
    const float* xr = x + (size_t)t * HDIM;
    float ss = 0.f;
    for (int h = threadIdx.x; h < HDIM; h += 256) { float v = xr[h]; ss += v * v; }
    __shared__ float red[4];
    #pragma unroll
    for (int off = 32; off; off >>= 1) ss += __shfl_down(ss, off, 64);
    int wid = threadIdx.x >> 6;
    if ((threadIdx.x & 63) == 0) red[wid] = ss;
    __syncthreads();
    if (threadIdx.x == 0) {
        float tot = red[0] + red[1] + red[2] + red[3];
        red[0] = rsqrtf(tot / (float)HDIM + EPS);
    }
    __syncthreads();
    float scale = red[0];
    for (int h = threadIdx.x; h < HDIM; h += 256)
        out[(size_t)t * HDIM + h] = xr[h] * scale * w[h];
}

// ---------------- tiled fp32 GEMM: C[M,Nc] = A[M,Kc] * B[Nc,Kc]^T (+C) ----------------
// All dims multiples of 64 (M=1024, Nc in {3072,768}, Kc in {768,1536}).
#define BM 64
#define BN 64
#define BKK 16

__global__ __launch_bounds__(256) void gemm_tn(const float* __restrict__ A,
                                               const float* __restrict__ Bw,
                                               float* __restrict__ C,
                                               int Nc, int Kc, int add_residual) {
    __shared__ float As[BKK][BM];
    __shared__ float Bs[BKK][BN];
    int tid = threadIdx.x;
    int tx = tid & 15, ty = tid >> 4;
    int row0 = blockIdx.y * BM, col0 = blockIdx.x * BN;
    int lr = tid >> 2;            // 0..63
    int lk = (tid & 3) * 4;       // 0,4,8,12
    float acc[4][4] = {};
    for (int k0 = 0; k0 < Kc; k0 += BKK) {
        float4 a4 = *reinterpret_cast<const float4*>(&A[(size_t)(row0 + lr) * Kc + k0 + lk]);
        As[lk + 0][lr] = a4.x; As[lk + 1][lr] = a4.y; As[lk + 2][lr] = a4.z; As[lk + 3][lr] = a4.w;
        float4 b4 = *reinterpret_cast<const float4*>(&Bw[(size_t)(col0 + lr) * Kc + k0 + lk]);
        Bs[lk + 0][lr] = b4.x; Bs[lk + 1][lr] = b4.y; Bs[lk + 2][lr] = b4.z; Bs[lk + 3][lr] = b4.w;
        __syncthreads();
        #pragma unroll
        for (int k = 0; k < BKK; ++k) {
            float a[4], b[4];
            #pragma unroll
            for (int i = 0; i < 4; ++i) a[i] = As[k][ty * 4 + i];
            #pragma unroll
            for (int j = 0; j < 4; ++j) b[j] = Bs[k][tx * 4 + j];
            #pragma unroll
            for (int i = 0; i < 4; ++i)
                #pragma unroll
                for (int j = 0; j < 4; ++j) acc[i][j] += a[i] * b[j];
        }
        __syncthreads();
    }
    #pragma unroll
    for (int i = 0; i < 4; ++i) {
        int r = row0 + ty * 4 + i;
        #pragma unroll
        for (int j = 0; j < 4; ++j) {
            int c = col0 + tx * 4 + j;
            float v = acc[i][j];
            if (add_residual) v += C[(size_t)r * Nc + c];
            C[(size_t)r * Nc + c] = v;
        }
    }
}

// ---------------- conv state shift + depthwise conv + silu ----------------
__global__ __launch_bounds__(256) void conv_kernel(const float* __restrict__ conv_states,
                                                   const float* __restrict__ conv_w,
                                                   const float* __restrict__ conv_b,
                                                   const float* __restrict__ proj,
                                                   float* __restrict__ out_conv,
                                                   float* __restrict__ hs, int l) {
    int gid = blockIdx.x * 256 + threadIdx.x;   // t*DIN + d
    int t = gid / DIN, d = gid - t * DIN;
    const float* cst = conv_states + ((size_t)l * TT * DIN + gid) * KDIM;
    float c0 = cst[1], c1 = cst[2], c2 = cst[3];
    float c3 = proj[(size_t)t * (2 * DIN) + d];
    float* oc = out_conv + ((size_t)l * TT * DIN + gid) * KDIM;
    oc[0] = c0; oc[1] = c1; oc[2] = c2; oc[3] = c3;
    const float* cw = conv_w + ((size_t)l * DIN + d) * KDIM;
    float v = c0 * cw[0] + c1 * cw[1] + c2 * cw[2] + c3 * cw[3] + conv_b[l * DIN + d];
    hs[gid] = v / (1.f + expf(-v));
}

// ---------------- x_proj: xdb[t,j] = sum_d hs[t,d]*xw[l,j,d]  (wave per (t,j)) ----------------
__global__ __launch_bounds__(256) void xproj_kernel(const float* __restrict__ hs,
                                                    const float* __restrict__ xw,
                                                    float* __restrict__ xdb, int l) {
    int wave = (blockIdx.x * 256 + threadIdx.x) >> 6;
    int lane = threadIdx.x & 63;
    if (wave >= TT * XDB_W) return;
    int t = wave / XDB_W, j = wave - t * XDB_W;
    const float* hr = hs + (size_t)t * DIN;
    const float* wr = xw + ((size_t)l * XDB_W + j) * DIN;
    float s = 0.f;
    #pragma unroll
    for (int d = lane; d < DIN; d += 64) s += hr[d] * wr[d];
    #pragma unroll
    for (int off = 32; off; off >>= 1) s += __shfl_down(s, off, 64);
    if (lane == 0) xdb[(size_t)t * XDB_W + j] = s;
}

// ---------------- dt_proj + softplus + SSM update + y + gating ----------------
__global__ __launch_bounds__(256) void ssm_kernel(const float* __restrict__ xdb,
                                                  const float* __restrict__ dtw,
                                                  const float* __restrict__ dtb,
                                                  const float* __restrict__ Alog,
                                                  const float* __restrict__ Dp,
                                                  const float* __restrict__ ssm_states,
                                                  const float* __restrict__ hs,
                                                  const float* __restrict__ proj,
                                                  float* __restrict__ out_ssm,
                                                  float* __restrict__ yg, int l) {
    __shared__ float sxdb[XDB_W];
    int blocks_per_t = DIN / 256;           // 6
    int t = blockIdx.x / blocks_per_t;
    int d = (blockIdx.x - t * blocks_per_t) * 256 + threadIdx.x;
    if (threadIdx.x < XDB_W) sxdb[threadIdx.x] = xdb[(size_t)t * XDB_W + threadIdx.x];
    __syncthreads();
    const float* wr = dtw + ((size_t)l * DIN + d) * RDIM;
    float acc = dtb[l * DIN + d];
    #pragma unroll
    for (int r = 0; r < RDIM; ++r) acc += sxdb[r] * wr[r];
    float dt = acc > 20.f ? acc : log1pf(expf(acc));
    float hv = hs[(size_t)t * DIN + d];
    const float* Ar = Alog + ((size_t)l * DIN + d) * NDIM;
    const float* ssr = ssm_states + ((size_t)l * TT * DIN + (size_t)t * DIN + d) * NDIM;
    float* oss = out_ssm + ((size_t)l * TT * DIN + (size_t)t * DIN + d) * NDIM;
    float y = 0.f;
    #pragma unroll
    for (int n = 0; n < NDIM; ++n) {
        float A = -expf(Ar[n]);
        float dA = expf(dt * A);
        float ssv = ssr[n] * dA + dt * sxdb[RDIM + n] * hv;
        oss[n] = ssv;
        y += ssv * sxdb[RDIM + NDIM + n];
    }
    y += Dp[l * DIN + d] * hv;
    float g = proj[(size_t)t * (2 * DIN) + DIN + d];
    float sg = g / (1.f + expf(-g));
    yg[(size_t)t * DIN + d] = y * sg;
}

// ---------------- launch ----------------

extern "C" void kernel_launch(void* const* d_in, const int* in_sizes, int n_in,
                              void* d_out, int out_size, void* d_ws, size_t ws_size,
                              hipStream_t stream) {
    const float* u           = (const float*)d_in[0];
    const float* conv_states = (const float*)d_in[1];
    const float* ssm_states  = (const float*)d_in[2];
    const float* in_proj_w   = (const float*)d_in[3];
    const float* conv_w      = (const float*)d_in[4];
    const float* conv_b      = (const float*)d_in[5];
    const float* x_proj_w    = (const float*)d_in[6];
    const float* dt_proj_w   = (const float*)d_in[7];
    const float* dt_proj_b   = (const float*)d_in[8];
    const float* A_log       = (const float*)d_in[9];
    const float* Dp          = (const float*)d_in[10];
    const float* out_proj_w  = (const float*)d_in[11];
    const float* norm_w      = (const float*)d_in[12];
    const float* norm_f_w    = (const float*)d_in[13];

    float* out_x    = (float*)d_out;                          // T*H
    float* out_conv = out_x + (size_t)TT * HDIM;              // L*T*DIN*K
    float* out_ssm  = out_conv + (size_t)LAYERS * TT * DIN * KDIM;

    float* ws = (float*)d_ws;
    float* x    = ws;                         // T*H
    float* hn   = x + (size_t)TT * HDIM;      // T*H
    float* proj = hn + (size_t)TT * HDIM;     // T*2*DIN
    float* hs   = proj + (size_t)TT * 2 * DIN;// T*DIN
    float* xdb  = hs + (size_t)TT * DIN;      // T*81
    float* yg   = xdb + (size_t)TT * XDB_W;   // T*DIN

    copy_kernel<<<1024, 256, 0, stream>>>(u, x, TT * HDIM);

    for (int l = 0; l < LAYERS; ++l) {
        rmsnorm_kernel<<<TT, 256, 0, stream>>>(x, norm_w + (size_t)l * HDIM, hn);
        gemm_tn<<<dim3(2 * DIN / BN, TT / BM), 256, 0, stream>>>(
            hn, in_proj_w + (size_t)l * 2 * DIN * HDIM, proj, 2 * DIN, HDIM, 0);
        conv_kernel<<<TT * DIN / 256, 256, 0, stream>>>(
            conv_states, conv_w, conv_b, proj, out_conv, hs, l);
        xproj_kernel<<<(TT * XDB_W + 3) / 4, 256, 0, stream>>>(hs, x_proj_w, xdb, l);
        ssm_kernel<<<TT * DIN / 256, 256, 0, stream>>>(
            xdb, dt_proj_w, dt_proj_b, A_log, Dp, ssm_states, hs, proj, out_ssm, yg, l);
        gemm_tn<<<dim3(HDIM / BN, TT / BM), 256, 0, stream>>>(
            yg, out_proj_w + (size_t)l * HDIM * DIN, x, HDIM, DIN, 1);
    }

    rmsnorm_kernel<<<TT, 256, 0, stream>>>(x, norm_f_w, out_x);
}

// Round 4
// 738.023 us; speedup vs baseline: 1.4674x; 1.4674x over previous
//
#include <hip/hip_runtime.h>
#include <hip/hip_bf16.h>
#include <math.h>

// Problem constants
#define LAYERS 2
#define HDIM 768
#define NDIM 16
#define KDIM 4
#define DIN 1536
#define RDIM 49
#define TT 1024           // B*P
#define XDB_W 81          // R + 2*N
#define EPS 1e-5f

typedef __hip_bfloat16 bf16;
using short8 = __attribute__((ext_vector_type(8))) short;   // 8 bf16 (4 VGPRs)
using f32x4  = __attribute__((ext_vector_type(4))) float;   // MFMA acc

__device__ __forceinline__ void gload_lds16(const void* g, void* l) {
    __builtin_amdgcn_global_load_lds(
        (const __attribute__((address_space(1))) void*)g,
        (__attribute__((address_space(3))) void*)l, 16, 0, 0);
}

// ---------------- utility kernels ----------------

__global__ __launch_bounds__(256) void copy_kernel(const float* __restrict__ src,
                                                   float* __restrict__ dst, int n) {
    int i = blockIdx.x * 256 + threadIdx.x;
    for (; i < n; i += gridDim.x * 256) dst[i] = src[i];
}

__global__ __launch_bounds__(256) void convert_f32_bf16(const float* __restrict__ src,
                                                        bf16* __restrict__ dst, int n) {
    int i = (blockIdx.x * 256 + threadIdx.x) * 4;
    int stride = gridDim.x * 256 * 4;
    for (; i < n; i += stride) {
        float4 v = *reinterpret_cast<const float4*>(&src[i]);
        bf16 o[4] = {__float2bfloat16(v.x), __float2bfloat16(v.y),
                     __float2bfloat16(v.z), __float2bfloat16(v.w)};
        *reinterpret_cast<ushort4*>(&dst[i]) = *reinterpret_cast<ushort4*>(o);
    }
}

// One block (256 threads) per row of length HDIM. OUT = float or bf16.
template <typename OUT>
__global__ __launch_bounds__(256) void rmsnorm_kernel(const float* __restrict__ x,
                                                      const float* __restrict__ w,
                                                      OUT* __restrict__ out) {
    int t = blockIdx.x;
    const float* xr = x + (size_t)t * HDIM;
    float ss = 0.f;
    for (int h = threadIdx.x; h < HDIM; h += 256) { float v = xr[h]; ss += v * v; }
    __shared__ float red[4];
    #pragma unroll
    for (int off = 32; off; off >>= 1) ss += __shfl_down(ss, off, 64);
    int wid = threadIdx.x >> 6;
    if ((threadIdx.x & 63) == 0) red[wid] = ss;
    __syncthreads();
    if (threadIdx.x == 0) {
        float tot = red[0] + red[1] + red[2] + red[3];
        red[0] = rsqrtf(tot / (float)HDIM + EPS);
    }
    __syncthreads();
    float scale = red[0];
    for (int h = threadIdx.x; h < HDIM; h += 256) {
        float v = xr[h] * scale * w[h];
        if constexpr (__is_same(OUT, bf16)) out[(size_t)t * HDIM + h] = __float2bfloat16(v);
        else                                out[(size_t)t * HDIM + h] = v;
    }
}

// ---------------- bf16 MFMA GEMM: C[M,NC] = A[M,KC] * B[NC,KC]^T (+C) ----------------
// A: [M][KC] bf16 row-major, B: [NC][KC] bf16 row-major (weight [out,in]).
// Block = 256 threads = 4 waves in 2x2; wave computes (BM/2)x(BN/2).
template<int BM, int BN, int KC, int NC, bool RES>
__global__ __launch_bounds__(256) void gemm_mfma(const bf16* __restrict__ A,
                                                 const bf16* __restrict__ B,
                                                 float* __restrict__ C) {
    constexpr int BK = 64;
    constexpr int FM = BM / 32, FN = BN / 32;      // 16x16 frags per wave
    __shared__ bf16 Asl[BM * BK];
    __shared__ bf16 Bsl[BN * BK];
    int tid = threadIdx.x;
    int lane = tid & 63;
    int wid = tid >> 6;
    int wr = wid >> 1, wc = wid & 1;
    int row0 = blockIdx.y * BM, col0 = blockIdx.x * BN;

    f32x4 acc[FM][FN] = {};

    for (int k0 = 0; k0 < KC; k0 += BK) {
        // stage A tile: BM rows x 64 bf16, 16B per thread-chunk, linear LDS
        #pragma unroll
        for (int it = 0; it < BM / 32; ++it) {
            int idx = it * 256 + tid;              // 16B chunk id
            int r = idx >> 3, kc = (idx & 7) * 8;
            gload_lds16(A + (size_t)(row0 + r) * KC + k0 + kc, &Asl[idx * 8]);
        }
        #pragma unroll
        for (int it = 0; it < BN / 32; ++it) {
            int idx = it * 256 + tid;
            int r = idx >> 3, kc = (idx & 7) * 8;
            gload_lds16(B + (size_t)(col0 + r) * KC + k0 + kc, &Bsl[idx * 8]);
        }
        __syncthreads();
        #pragma unroll
        for (int kk = 0; kk < 2; ++kk) {
            int krow = kk * 32 + (lane >> 4) * 8;
            short8 af[FM], bfr[FN];
            #pragma unroll
            for (int i = 0; i < FM; ++i)
                af[i] = *reinterpret_cast<const short8*>(
                    &Asl[(wr * (BM / 2) + i * 16 + (lane & 15)) * BK + krow]);
            #pragma unroll
            for (int j = 0; j < FN; ++j)
                bfr[j] = *reinterpret_cast<const short8*>(
                    &Bsl[(wc * (BN / 2) + j * 16 + (lane & 15)) * BK + krow]);
            #pragma unroll
            for (int i = 0; i < FM; ++i)
                #pragma unroll
                for (int j = 0; j < FN; ++j)
                    acc[i][j] = __builtin_amdgcn_mfma_f32_16x16x32_bf16(
                        af[i], bfr[j], acc[i][j], 0, 0, 0);
        }
        __syncthreads();
    }
    // epilogue: D row=(lane>>4)*4+r, col=lane&15 within each 16x16 frag
    #pragma unroll
    for (int i = 0; i < FM; ++i)
        #pragma unroll
        for (int j = 0; j < FN; ++j)
            #pragma unroll
            for (int r = 0; r < 4; ++r) {
                int row = row0 + wr * (BM / 2) + i * 16 + (lane >> 4) * 4 + r;
                int col = col0 + wc * (BN / 2) + j * 16 + (lane & 15);
                float v = acc[i][j][r];
                if (RES) v += C[(size_t)row * NC + col];
                C[(size_t)row * NC + col] = v;
            }
}

// ---------------- conv state shift + depthwise conv + silu ----------------
__global__ __launch_bounds__(256) void conv_kernel(const float* __restrict__ conv_states,
                                                   const float* __restrict__ conv_w,
                                                   const float* __restrict__ conv_b,
                                                   const float* __restrict__ proj,
                                                   float* __restrict__ out_conv,
                                                   float* __restrict__ hs, int l) {
    int gid = blockIdx.x * 256 + threadIdx.x;   // t*DIN + d
    int t = gid / DIN, d = gid - t * DIN;
    const float* cst = conv_states + ((size_t)l * TT * DIN + gid) * KDIM;
    float4 c = *reinterpret_cast<const float4*>(cst);
    float c3 = proj[(size_t)t * (2 * DIN) + d];
    float4 o = make_float4(c.y, c.z, c.w, c3);
    *reinterpret_cast<float4*>(out_conv + ((size_t)l * TT * DIN + gid) * KDIM) = o;
    float4 cw = *reinterpret_cast<const float4*>(conv_w + ((size_t)l * DIN + d) * KDIM);
    float v = c.y * cw.x + c.z * cw.y + c.w * cw.z + c3 * cw.w + conv_b[l * DIN + d];
    hs[gid] = v / (1.f + expf(-v));
}

// ---------------- x_proj: xdb[t,j] = sum_d hs[t,d]*xw[l,j,d]  (wave per (t,j)) ----------------
__global__ __launch_bounds__(256) void xproj_kernel(const float* __restrict__ hs,
                                                    const float* __restrict__ xw,
                                                    float* __restrict__ xdb, int l) {
    int wave = (blockIdx.x * 256 + threadIdx.x) >> 6;
    int lane = threadIdx.x & 63;
    if (wave >= TT * XDB_W) return;
    int t = wave / XDB_W, j = wave - t * XDB_W;
    const float* hr = hs + (size_t)t * DIN;
    const float* wr = xw + ((size_t)l * XDB_W + j) * DIN;
    float s = 0.f;
    #pragma unroll
    for (int d = lane * 4; d < DIN; d += 256) {
        float4 hv = *reinterpret_cast<const float4*>(&hr[d]);
        float4 wv = *reinterpret_cast<const float4*>(&wr[d]);
        s += hv.x * wv.x + hv.y * wv.y + hv.z * wv.z + hv.w * wv.w;
    }
    #pragma unroll
    for (int off = 32; off; off >>= 1) s += __shfl_down(s, off, 64);
    if (lane == 0) xdb[(size_t)t * XDB_W + j] = s;
}

// ---------------- dt_proj + softplus + SSM update + y + gating ----------------
__global__ __launch_bounds__(256) void ssm_kernel(const float* __restrict__ xdb,
                                                  const float* __restrict__ dtw,
                                                  const float* __restrict__ dtb,
                                                  const float* __restrict__ Alog,
                                                  const float* __restrict__ Dp,
                                                  const float* __restrict__ ssm_states,
                                                  const float* __restrict__ hs,
                                                  const float* __restrict__ proj,
                                                  float* __restrict__ out_ssm,
                                                  bf16* __restrict__ yg_bf, int l) {
    __shared__ float sxdb[XDB_W];
    int blocks_per_t = DIN / 256;           // 6
    int t = blockIdx.x / blocks_per_t;
    int d = (blockIdx.x - t * blocks_per_t) * 256 + threadIdx.x;
    if (threadIdx.x < XDB_W) sxdb[threadIdx.x] = xdb[(size_t)t * XDB_W + threadIdx.x];
    __syncthreads();
    const float* wr = dtw + ((size_t)l * DIN + d) * RDIM;
    float acc = dtb[l * DIN + d];
    #pragma unroll
    for (int r = 0; r < RDIM; ++r) acc += sxdb[r] * wr[r];
    float dt = acc > 20.f ? acc : log1pf(expf(acc));
    float hv = hs[(size_t)t * DIN + d];
    const float* Ar = Alog + ((size_t)l * DIN + d) * NDIM;
    const float* ssr = ssm_states + ((size_t)l * TT * DIN + (size_t)t * DIN + d) * NDIM;
    float* oss = out_ssm + ((size_t)l * TT * DIN + (size_t)t * DIN + d) * NDIM;
    float y = 0.f;
    #pragma unroll
    for (int n = 0; n < NDIM; ++n) {
        float A = -expf(Ar[n]);
        float dA = expf(dt * A);
        float ssv = ssr[n] * dA + dt * sxdb[RDIM + n] * hv;
        oss[n] = ssv;
        y += ssv * sxdb[RDIM + NDIM + n];
    }
    y += Dp[l * DIN + d] * hv;
    float g = proj[(size_t)t * (2 * DIN) + DIN + d];
    float sg = g / (1.f + expf(-g));
    yg_bf[(size_t)t * DIN + d] = __float2bfloat16(y * sg);
}

// ---------------- launch ----------------

extern "C" void kernel_launch(void* const* d_in, const int* in_sizes, int n_in,
                              void* d_out, int out_size, void* d_ws, size_t ws_size,
                              hipStream_t stream) {
    const float* u           = (const float*)d_in[0];
    const float* conv_states = (const float*)d_in[1];
    const float* ssm_states  = (const float*)d_in[2];
    const float* in_proj_w   = (const float*)d_in[3];
    const float* conv_w      = (const float*)d_in[4];
    const float* conv_b      = (const float*)d_in[5];
    const float* x_proj_w    = (const float*)d_in[6];
    const float* dt_proj_w   = (const float*)d_in[7];
    const float* dt_proj_b   = (const float*)d_in[8];
    const float* A_log       = (const float*)d_in[9];
    const float* Dp          = (const float*)d_in[10];
    const float* out_proj_w  = (const float*)d_in[11];
    const float* norm_w      = (const float*)d_in[12];
    const float* norm_f_w    = (const float*)d_in[13];

    float* out_x    = (float*)d_out;                          // T*H
    float* out_conv = out_x + (size_t)TT * HDIM;              // L*T*DIN*K
    float* out_ssm  = out_conv + (size_t)LAYERS * TT * DIN * KDIM;

    float* ws = (float*)d_ws;
    float* x    = ws;                          // T*H fp32
    float* proj = x + (size_t)TT * HDIM;       // T*2*DIN fp32
    float* hs   = proj + (size_t)TT * 2 * DIN; // T*DIN fp32
    float* xdb  = hs + (size_t)TT * DIN;       // T*81 fp32
    float* fend = xdb + (size_t)TT * XDB_W;
    bf16* hn_bf  = (bf16*)fend;                                    // T*H
    bf16* yg_bf  = hn_bf + (size_t)TT * HDIM;                      // T*DIN
    bf16* w_in_bf  = yg_bf + (size_t)TT * DIN;                     // L*2DIN*H
    bf16* w_out_bf = w_in_bf + (size_t)LAYERS * 2 * DIN * HDIM;    // L*H*DIN

    copy_kernel<<<1024, 256, 0, stream>>>(u, x, TT * HDIM);
    convert_f32_bf16<<<1024, 256, 0, stream>>>(in_proj_w, w_in_bf, LAYERS * 2 * DIN * HDIM);
    convert_f32_bf16<<<1024, 256, 0, stream>>>(out_proj_w, w_out_bf, LAYERS * HDIM * DIN);

    for (int l = 0; l < LAYERS; ++l) {
        rmsnorm_kernel<bf16><<<TT, 256, 0, stream>>>(x, norm_w + (size_t)l * HDIM, hn_bf);
        gemm_mfma<128, 128, HDIM, 2 * DIN, false><<<dim3(2 * DIN / 128, TT / 128), 256, 0, stream>>>(
            hn_bf, w_in_bf + (size_t)l * 2 * DIN * HDIM, proj);
        conv_kernel<<<TT * DIN / 256, 256, 0, stream>>>(
            conv_states, conv_w, conv_b, proj, out_conv, hs, l);
        xproj_kernel<<<(TT * XDB_W + 3) / 4, 256, 0, stream>>>(hs, x_proj_w, xdb, l);
        ssm_kernel<<<TT * DIN / 256, 256, 0, stream>>>(
            xdb, dt_proj_w, dt_proj_b, A_log, Dp, ssm_states, hs, proj, out_ssm, yg_bf, l);
        gemm_mfma<64, 64, DIN, HDIM, true><<<dim3(HDIM / 64, TT / 64), 256, 0, stream>>>(
            yg_bf, w_out_bf + (size_t)l * HDIM * DIN, x);
    }

    rmsnorm_kernel<float><<<TT, 256, 0, stream>>>(x, norm_f_w, out_x);
}